// Round 4
// baseline (688.590 us; speedup 1.0000x reference)
//
#include <hip/hip_runtime.h>
#include <math.h>

// Problem constants
#define BATCH 16
#define G 5           // feature groups
#define CI 4          // in channels per group  (20/5)
#define CO 8          // out channels per group (40/5)
#define HW 384
#define PADD 2
#define TLE 32
#define IT 36         // input tile with halo: 32 + 2*2

typedef _Float16 h2 __attribute__((ext_vector_type(2)));

// Separable basis table: d[g][di][tap], tap 0..4 centered (zero outside support).
// 75 floats in workspace. Alphas are consumed directly from the input buffer.
__global__ void gen_dtable(const float* __restrict__ scales, float* __restrict__ d) {
    int idx = blockIdx.x * blockDim.x + threadIdx.x;
    if (idx >= G * 15) return;
    int tap = idx % 5; int r = idx / 5;
    int di = r % 3;    int s = r / 3;

    float mn = 0.2f * (float)s;
    float mx = mn + 0.2f;
    float sigma = 0.5f * (mx - mn) * tanhf(scales[s]) + 0.5f * (mn + mx);
    int fs = (s < 3) ? 1 : 2;          // static half filter sizes [1,1,1,2,2]
    int x = tap - 2;

    float val = 0.f;
    if (x >= -fs && x <= fs) {
        float inv2s2 = 1.f / (2.f * sigma * sigma);
        float Gs = 0.f;
        for (int t = -fs; t <= fs; ++t) Gs += expf(-(float)(t * t) * inv2s2);
        float gg = expf(-(float)(x * x) * inv2s2) / Gs;
        const float sqrt2 = 1.41421356237309505f;
        float c = -1.f / (sigma * sqrt2);
        float u = (float)x / (sigma * sqrt2);
        if (di == 0)      val = gg;
        else if (di == 1) val = c * 2.f * u * gg;
        else              val = c * c * (4.f * u * u - 2.f) * gg;
    }
    d[(s * 3 + di) * 5 + tap] = val;
}

// Separable conv: stage -> y-convs (12 f16 planes in LDS) -> x-convs + alpha mix.
// Block: 32x32 outputs, 256 threads; thread owns 1y x 4x x 8o.
__global__ __launch_bounds__(256) void conv_kernel(const float* __restrict__ in,
                                                   const float* __restrict__ dt,
                                                   const float* __restrict__ alphas,
                                                   float* __restrict__ out) {
    __shared__ float s_in[CI][IT][IT];                 // 20736 B
    __shared__ unsigned short s_v[CI * 3][TLE][IT];    // 27648 B (f16), row 72 B (8B-aligned)

    const int tileX = blockIdx.x * TLE;
    const int tileY = blockIdx.y * TLE;
    const int bz = blockIdx.z;           // b*G + g
    const int g = bz % G;
    const int b = bz / G;
    const int tid = threadIdx.x;

    // --- phase 1: stage input tile (with zero halo at borders) ---
    const float* inb = in + ((size_t)b * (G * CI) + g * CI) * (HW * HW);
    for (int l = tid; l < CI * IT * IT; l += 256) {
        int c = l / (IT * IT);
        int r = l - c * (IT * IT);
        int ly = r / IT;
        int lx = r - ly * IT;
        int gy = tileY - PADD + ly;
        int gx = tileX - PADD + lx;
        float v = 0.f;
        if ((unsigned)gy < (unsigned)HW && (unsigned)gx < (unsigned)HW)
            v = inb[c * (HW * HW) + gy * HW + gx];
        s_in[c][ly][lx] = v;
    }

    // 1D basis coefficients for this group (block-uniform -> SGPR)
    float D[3][5];
    {
        const float* dg = dt + g * 15;
        #pragma unroll
        for (int di = 0; di < 3; ++di)
            #pragma unroll
            for (int t = 0; t < 5; ++t) D[di][t] = dg[di * 5 + t];
    }
    __syncthreads();

    // --- phase 2: vertical (y) convolutions -> s_v planes, f16 ---
    // tasks: (y 0..31) x (q 0..8 : 4-wide x' chunk), 288 tasks over 256 threads
    #pragma unroll
    for (int rnd = 0; rnd < 2; ++rnd) {
        int s = tid + rnd * 256;
        if (s < 288) {
            int y = (s * 57) >> 9;       // == s/9 for s<288
            int q = s - y * 9;
            #pragma unroll
            for (int i = 0; i < CI; ++i) {
                float4 rr[5];
                #pragma unroll
                for (int r = 0; r < 5; ++r)
                    rr[r] = *(const float4*)&s_in[i][y + r][q * 4];
                #pragma unroll
                for (int di = 0; di < 3; ++di) {
                    float v0 = 0.f, v1 = 0.f, v2 = 0.f, v3 = 0.f;
                    #pragma unroll
                    for (int r = 0; r < 5; ++r) {
                        v0 += D[di][r] * rr[r].x;
                        v1 += D[di][r] * rr[r].y;
                        v2 += D[di][r] * rr[r].z;
                        v3 += D[di][r] * rr[r].w;
                    }
                    union { uint2 u2; h2 h[2]; } cv;
                    cv.h[0][0] = (_Float16)v0; cv.h[0][1] = (_Float16)v1;
                    cv.h[1][0] = (_Float16)v2; cv.h[1][1] = (_Float16)v3;
                    *(uint2*)&s_v[i * 3 + di][y][q * 4] = cv.u2;
                }
            }
        }
    }
    __syncthreads();

    // --- phase 3: horizontal (x) convolutions + channel mix ---
    const int xc = tid & 7;        // x-chunk 0..7
    const int ty = tid >> 3;       // output row 0..31
    const int xl0 = xc * 4;        // local x of first output

    float acc[CO][4];
    #pragma unroll
    for (int o = 0; o < CO; ++o)
        #pragma unroll
        for (int e = 0; e < 4; ++e) acc[o][e] = 0.f;

    const float* al = alphas + (size_t)g * (6 * CI * CO);   // [n][i][o]

    for (int i = 0; i < CI; ++i) {
        #pragma unroll
        for (int di = 0; di < 3; ++di) {
            union { uint2 u2; h2 h[2]; } c0, c1;
            c0.u2 = *(const uint2*)&s_v[i * 3 + di][ty][xl0];
            c1.u2 = *(const uint2*)&s_v[i * 3 + di][ty][xl0 + 4];
            float uu[8];
            uu[0] = (float)c0.h[0][0]; uu[1] = (float)c0.h[0][1];
            uu[2] = (float)c0.h[1][0]; uu[3] = (float)c0.h[1][1];
            uu[4] = (float)c1.h[0][0]; uu[5] = (float)c1.h[0][1];
            uu[6] = (float)c1.h[1][0]; uu[7] = (float)c1.h[1][1];
            #pragma unroll
            for (int dj = 0; dj < 3 - di; ++dj) {
                const int n = (di == 0) ? dj : ((di == 1) ? 3 + dj : 5);
                float yv[4];
                #pragma unroll
                for (int e = 0; e < 4; ++e) {
                    float a = 0.f;
                    #pragma unroll
                    for (int kx = 0; kx < 5; ++kx) a += D[dj][kx] * uu[e + kx];
                    yv[e] = a;
                }
                const float* a8 = al + (n * CI + i) * CO;   // block-uniform -> SGPR
                #pragma unroll
                for (int o = 0; o < CO; ++o) {
                    float wv = a8[o];
                    #pragma unroll
                    for (int e = 0; e < 4; ++e) acc[o][e] += wv * yv[e];
                }
            }
        }
    }

    // --- epilogue: 8 output channels x 4 consecutive x as float4 ---
    const int oy = tileY + ty;
    float* outb = out + (((size_t)b * (G * CO) + g * CO) * HW + oy) * HW + tileX + xl0;
    #pragma unroll
    for (int o = 0; o < CO; ++o) {
        float4 rr;
        rr.x = acc[o][0];
        rr.y = acc[o][1];
        rr.z = acc[o][2];
        rr.w = acc[o][3];
        *(float4*)(outb + (size_t)o * (HW * HW)) = rr;
    }
}

extern "C" void kernel_launch(void* const* d_in, const int* in_sizes, int n_in,
                              void* d_out, int out_size, void* d_ws, size_t ws_size,
                              hipStream_t stream) {
    const float* data   = (const float*)d_in[0];
    const float* alphas = (const float*)d_in[1];
    const float* scales = (const float*)d_in[2];
    float* out = (float*)d_out;
    float* dt  = (float*)d_ws;   // 75 floats

    gen_dtable<<<1, 128, 0, stream>>>(scales, dt);

    dim3 grid(HW / TLE, HW / TLE, BATCH * G);   // (12, 12, 80)
    conv_kernel<<<grid, 256, 0, stream>>>(data, dt, alphas, out);
}